// Round 8
// baseline (794.461 us; speedup 1.0000x reference)
//
#include <hip/hip_runtime.h>
#include <math.h>

#define NN 50000
#define EE 600000
#define GG 250
#define HH 128
#define NB 512
#define NT 256
#define NTH (NB * NT)

typedef __attribute__((ext_vector_type(8))) short s16x8;
typedef __attribute__((ext_vector_type(8))) unsigned short u16x8;
typedef __attribute__((ext_vector_type(4))) unsigned short u16x4;
typedef __attribute__((ext_vector_type(4))) float f32x4;

__device__ __forceinline__ float b2f(unsigned short u) {
  union { unsigned int i; float f; } v; v.i = ((unsigned int)u) << 16; return v.f;
}
__device__ __forceinline__ unsigned short f2b(float f) {
  union { float f; unsigned int i; } v; v.f = f;
  unsigned int x = v.i;
  unsigned int r = (x + 0x7FFFu + ((x >> 16) & 1u)) >> 16;   // RNE, finite inputs
  return (unsigned short)r;
}

// ---- device-scope grid barrier: all NB blocks co-resident by construction ----
__device__ __forceinline__ void gbar(int* c) {
  __syncthreads();
  if (threadIdx.x == 0) {
    __threadfence();                       // release my writes (device scope)
    atomicAdd(c, 1);
    int it = 0;
    while (__hip_atomic_load(c, __ATOMIC_RELAXED, __HIP_MEMORY_SCOPE_AGENT) < NB) {
      __builtin_amdgcn_s_sleep(4);
      if (++it > (1 << 22)) break;         // bounded: fail visibly, never hang
    }
    __threadfence();                       // acquire + L1 invalidate
  }
  __syncthreads();
}

__global__ void zc_k(int* bar) { bar[threadIdx.x] = 0; }

// ---------- mean aggregation phase ----------
__device__ __forceinline__ void agg_phase(const unsigned short* __restrict__ hb,
                                          const int* __restrict__ rowptr,
                                          const int* __restrict__ eidx,
                                          unsigned short* __restrict__ aggb) {
  int tid = threadIdx.x;
  int lane = tid & 63, wid = tid >> 6;
  int sub = lane >> 4, l16 = lane & 15;
  int base = sub * 16;
  int gw = blockIdx.x * 4 + wid;                     // global wave id
  for (int q = gw; q < NN / 4; q += NB * 4) {
    int node = q * 4 + sub;
    int start = rowptr[node], end = rowptr[node + 1];
    float acc[8] = {0.f, 0.f, 0.f, 0.f, 0.f, 0.f, 0.f, 0.f};
    for (int c = start; c < end; c += 16) {
      int ecl = c + l16; if (ecl > end - 1) ecl = end - 1;
      int myidx = eidx[ecl];                         // 64B coalesced per group
      u16x8 rv[16];
      #pragma unroll
      for (int t = 0; t < 16; ++t) {
        int s = __shfl(myidx, base + t);
        u16x8 z = {0, 0, 0, 0, 0, 0, 0, 0};
        rv[t] = (c + t < end) ? *(const u16x8*)&hb[s * HH + l16 * 8] : z;
      }
      #pragma unroll
      for (int t = 0; t < 16; ++t) {
        #pragma unroll
        for (int j = 0; j < 8; ++j) acc[j] += b2f(rv[t][j]);
      }
    }
    int cnt = end - start;
    float inv = 1.f / (float)(cnt > 0 ? cnt : 1);
    u16x8 o;
    #pragma unroll
    for (int j = 0; j < 8; ++j) o[j] = f2b(acc[j] * inv);
    *(u16x8*)&aggb[node * HH + l16 * 8] = o;
  }
}

// ---------- MFMA sage phase (LDS-staged [Wl^T;Wr^T], 64KB) ----------
__device__ __forceinline__ void sage_phase(
    const unsigned short* __restrict__ aggb, const unsigned short* __restrict__ hb,
    const unsigned short* __restrict__ WlT, const float* __restrict__ bl,
    unsigned short* __restrict__ hout, float* __restrict__ hgmax,
    unsigned short* sW) {
  int tid = threadIdx.x;
  #pragma unroll
  for (int i = 0; i < 16; ++i) {                     // stage 64KB, XOR-swizzled units
    int u = i * 256 + tid;
    int row = u >> 4, unit = u & 15;
    u16x8 w = *(const u16x8*)&WlT[row * 128 + unit * 8];
    *(u16x8*)&sW[row * 128 + ((unit ^ (row & 7)) * 8)] = w;
  }
  __syncthreads();
  int lane = tid & 63, wid = tid >> 6;
  int l16 = lane & 15, hi = lane >> 4;
  int rb = blockIdx.x;
  if (rb * 128 < NN) {                               // 391 active blocks
    int rbase = rb * 128 + wid * 32;
    s16x8 aA[2][4], aH[2][4];
    #pragma unroll
    for (int rt = 0; rt < 2; ++rt) {
      int ar = rbase + rt * 16 + l16; if (ar > NN - 1) ar = NN - 1;
      #pragma unroll
      for (int kk = 0; kk < 4; ++kk) {
        aA[rt][kk] = *(const s16x8*)&aggb[ar * HH + kk * 32 + hi * 8];
        aH[rt][kk] = *(const s16x8*)&hb[ar * HH + kk * 32 + hi * 8];
      }
    }
    f32x4 acc[2][8];
    #pragma unroll
    for (int rt = 0; rt < 2; ++rt)
      #pragma unroll
      for (int cc = 0; cc < 8; ++cc) acc[rt][cc] = (f32x4){0.f, 0.f, 0.f, 0.f};
    #pragma unroll
    for (int cc = 0; cc < 8; ++cc) {
      int brow = cc * 16 + l16;
      int bb = brow * 128;
      int sw = brow & 7;
      #pragma unroll
      for (int kk = 0; kk < 4; ++kk) {
        int un = (kk * 4 + hi) ^ sw;
        s16x8 bL = *(const s16x8*)&sW[bb + un * 8];
        acc[0][cc] = __builtin_amdgcn_mfma_f32_16x16x32_bf16(aA[0][kk], bL, acc[0][cc], 0, 0, 0);
        acc[1][cc] = __builtin_amdgcn_mfma_f32_16x16x32_bf16(aA[1][kk], bL, acc[1][cc], 0, 0, 0);
        s16x8 bR = *(const s16x8*)&sW[16384 + bb + un * 8];
        acc[0][cc] = __builtin_amdgcn_mfma_f32_16x16x32_bf16(aH[0][kk], bR, acc[0][cc], 0, 0, 0);
        acc[1][cc] = __builtin_amdgcn_mfma_f32_16x16x32_bf16(aH[1][kk], bR, acc[1][cc], 0, 0, 0);
      }
    }
    #pragma unroll
    for (int rt = 0; rt < 2; ++rt) {
      int rtb = rbase + rt * 16;
      float v[8][4];
      float ss[4] = {0.f, 0.f, 0.f, 0.f};
      #pragma unroll
      for (int cc = 0; cc < 8; ++cc) {
        float bb = bl[cc * 16 + l16];
        #pragma unroll
        for (int i = 0; i < 4; ++i) {
          float t = acc[rt][cc][i] + bb;
          v[cc][i] = t;
          ss[i] += t * t;
        }
      }
      #pragma unroll
      for (int m = 1; m < 16; m <<= 1) {
        #pragma unroll
        for (int i = 0; i < 4; ++i) ss[i] += __shfl_xor(ss[i], m);
      }
      float inv[4];
      #pragma unroll
      for (int i = 0; i < 4; ++i) inv[i] = 1.f / fmaxf(sqrtf(ss[i]), 1e-12f);
      #pragma unroll
      for (int cc = 0; cc < 8; ++cc) {
        #pragma unroll
        for (int i = 0; i < 4; ++i) {
          int row = rtb + hi * 4 + i;
          if (row < NN)
            hout[row * HH + cc * 16 + l16] = f2b(fmaxf(v[cc][i] * inv[i], 0.f));
        }
      }
      if (hgmax) {
        int r4 = rtb + hi * 4;
        if (r4 < NN) {
          int g = r4 / 200;                          // 4-row strips never cross graphs
          #pragma unroll
          for (int cc = 0; cc < 8; ++cc) {
            float vm = 0.f;                          // relu floor
            #pragma unroll
            for (int i = 0; i < 4; ++i)
              if (r4 + i < NN) vm = fmaxf(vm, fmaxf(v[cc][i] * inv[i], 0.f));
            atomicMax((int*)&hgmax[g * HH + cc * 16 + l16], __float_as_int(vm));
          }
        }
      }
    }
  }
}

// ---------- the whole network in one kernel ----------
__global__ __launch_bounds__(NT, 2) void mega_k(
    const float* __restrict__ x, const int* __restrict__ src, const int* __restrict__ dst,
    const int* __restrict__ batch,
    const float* __restrict__ W1l, const float* __restrict__ b1l, const float* __restrict__ W1r,
    const float* __restrict__ W2l, const float* __restrict__ b2l, const float* __restrict__ W2r,
    const float* __restrict__ W3l, const float* __restrict__ b3l, const float* __restrict__ W3r,
    const float* __restrict__ Wn, const float* __restrict__ bn,
    const float* __restrict__ Wl2, const float* __restrict__ bl2,
    const float* __restrict__ Wl3, const float* __restrict__ bl3,
    int* bar, int* deg, int* excl, int* bsum, int* rowptr, int* wp, int* root, int* eidx,
    unsigned short* WT, unsigned short* xb, unsigned short* aggb,
    unsigned short* h1, unsigned short* h2, float* hg,
    float* __restrict__ out) {
  __shared__ unsigned short sW_[32768];              // 64KB -> exactly 2 blocks/CU
  int tid = threadIdx.x, bid = blockIdx.x;
  int gtid = bid * NT + tid;

  // ---- P0: cvt_x | cvtW | root | zero-deg | zero-hg ----
  const int C_X = NN * HH / 4;                       // 1,600,000
  const int C_W = 6 * 128 * 128;                     // 98,304
  const int C_R = NN;
  const int C_D = NN / 4;
  const int C_H = GG * HH / 4;
  const int C_T = C_X + C_W + C_R + C_D + C_H;
  for (int u = gtid; u < C_T; u += NTH) {
    if (u < C_X) {
      float4 v = *(const float4*)&x[u * 4];
      u16x4 o; o[0] = f2b(v.x); o[1] = f2b(v.y); o[2] = f2b(v.z); o[3] = f2b(v.w);
      *(u16x4*)&xb[u * 4] = o;
    } else if (u < C_X + C_W) {
      int idx = u - C_X;
      int w = idx >> 14, r = idx & 16383;
      int j = r >> 7, k = r & 127;
      const float* W = (w == 0) ? W1l : (w == 1) ? W1r : (w == 2) ? W2l
                       : (w == 3) ? W2r : (w == 4) ? W3l : W3r;
      WT[idx] = f2b(W[k * 128 + j]);                 // WT[w][col][k]
    } else if (u < C_X + C_W + C_R) {
      int n = u - (C_X + C_W);
      int bg = batch[n];
      if (n == 0 || batch[n - 1] != bg) root[bg] = n;
    } else if (u < C_X + C_W + C_R + C_D) {
      int n = u - (C_X + C_W + C_R);
      *(int4*)&deg[n * 4] = (int4){0, 0, 0, 0};
    } else {
      int n = u - (C_X + C_W + C_R + C_D);
      *(float4*)&hg[n * 4] = (float4){0.f, 0.f, 0.f, 0.f};
    }
  }
  gbar(&bar[0 * 64]);

  // ---- P1: histogram ----
  for (int e = gtid; e < EE; e += NTH) atomicAdd(&deg[dst[e]], 1);
  gbar(&bar[1 * 64]);

  // ---- P2: per-chunk scan (49 chunks x 1024) ----
  if (bid < 49) {
    int base = bid * 1024 + tid * 4;
    int4 d = {0, 0, 0, 0};
    if (base < NN) d = *(const int4*)&deg[base];     // NN%4==0: all-or-nothing
    int p1 = d.x + d.y, p2 = p1 + d.z, tt = p2 + d.w;
    int lane = tid & 63, wv = tid >> 6;
    int sc = tt;
    #pragma unroll
    for (int dd = 1; dd < 64; dd <<= 1) { int y = __shfl_up(sc, dd); if (lane >= dd) sc += y; }
    int* sWi = (int*)sW_;
    if (lane == 63) sWi[wv] = sc;
    __syncthreads();
    int wpre = 0;
    #pragma unroll
    for (int w2 = 0; w2 < 4; ++w2) wpre += (w2 < wv) ? sWi[w2] : 0;
    int ex = wpre + sc - tt;
    if (base < NN) {
      int4 o; o.x = ex; o.y = ex + d.x; o.z = ex + p1; o.w = ex + p2;
      *(int4*)&excl[base] = o;
    }
    if (tid == NT - 1) bsum[bid] = wpre + sc;
  }
  gbar(&bar[2 * 64]);

  // ---- P3: combine scans -> rowptr, wp ----
  {
    int* sWi = (int*)sW_;
    if (tid < 64) {
      int v = (tid < 49) ? bsum[tid] : 0;
      int s = v;
      #pragma unroll
      for (int dd = 1; dd < 64; dd <<= 1) { int y = __shfl_up(s, dd); if (tid >= dd) s += y; }
      sWi[tid] = s - v;
    }
    __syncthreads();
    for (int i = gtid; i < NN; i += NTH) {
      int r = excl[i] + sWi[i >> 10];
      rowptr[i] = r; wp[i] = r;
    }
    if (gtid == 0) rowptr[NN] = EE;
  }
  gbar(&bar[3 * 64]);

  // ---- P4: scatter edges into CSR ----
  for (int e = gtid; e < EE; e += NTH) {
    int p = atomicAdd(&wp[dst[e]], 1);
    eidx[p] = src[e];
  }
  gbar(&bar[4 * 64]);

  // ---- 3 SAGE layers ----
  agg_phase(xb, rowptr, eidx, aggb);
  gbar(&bar[5 * 64]);
  sage_phase(aggb, xb, WT + 0 * 16384, b1l, h1, nullptr, sW_);
  gbar(&bar[6 * 64]);
  agg_phase(h1, rowptr, eidx, aggb);
  gbar(&bar[7 * 64]);
  sage_phase(aggb, h1, WT + 2 * 16384, b2l, h2, nullptr, sW_);
  gbar(&bar[8 * 64]);
  agg_phase(h2, rowptr, eidx, aggb);
  gbar(&bar[9 * 64]);
  sage_phase(aggb, h2, WT + 4 * 16384, b3l, h1, hg, sW_);
  gbar(&bar[10 * 64]);

  // ---- P11: final (news + lin2 + lin3 + sigmoid), one block per graph ----
  if (bid < GG) {
    float* sWf = (float*)sW_;
    int g = bid;
    int rt = root[g];
    if (tid < 128) {
      sWf[tid] = hg[g * HH + tid];
      sWf[128 + tid] = x[rt * HH + tid];
    }
    __syncthreads();
    if (tid < 128) {
      int j = tid;
      float acc2 = bl2[j];
      float accn = bn[j];
      for (int k = 0; k < 128; ++k) {
        acc2 += sWf[k] * Wl2[k * HH + j];
        accn += sWf[128 + k] * Wn[k * HH + j];
      }
      float c = fmaxf(acc2, 0.f) * Wl3[j] + fmaxf(accn, 0.f) * Wl3[HH + j];
      #pragma unroll
      for (int d = 1; d < 64; d <<= 1) c += __shfl_xor(c, d);
      if ((j & 63) == 0) sWf[256 + (j >> 6)] = c;
    }
    __syncthreads();
    if (tid == 0) out[g] = 1.f / (1.f + expf(-(sWf[256] + sWf[257] + bl3[0])));
  }
}

extern "C" void kernel_launch(void* const* d_in, const int* in_sizes, int n_in,
                              void* d_out, int out_size, void* d_ws, size_t ws_size,
                              hipStream_t stream) {
  const float* x     = (const float*)d_in[0];
  const int*   adj   = (const int*)d_in[1];
  const int*   batch = (const int*)d_in[2];
  const float *W1l = (const float*)d_in[3],  *b1l = (const float*)d_in[4],  *W1r = (const float*)d_in[5];
  const float *W2l = (const float*)d_in[6],  *b2l = (const float*)d_in[7],  *W2r = (const float*)d_in[8];
  const float *W3l = (const float*)d_in[9],  *b3l = (const float*)d_in[10], *W3r = (const float*)d_in[11];
  const float *Wnews = (const float*)d_in[12], *bnews = (const float*)d_in[13];
  const float *Wlin2 = (const float*)d_in[14], *blin2 = (const float*)d_in[15];
  const float *Wlin3 = (const float*)d_in[16], *blin3 = (const float*)d_in[17];
  float* out = (float*)d_out;

  const int* srcp = adj;
  const int* dstp = adj + EE;

  char* ws = (char*)d_ws;
  size_t off = 0;
  auto alloc = [&](size_t bytes) -> void* {
    void* p = ws + off;
    off = (off + bytes + 255) & ~(size_t)255;
    return p;
  };
  int*   bar    = (int*)alloc(sizeof(int) * 1024);
  int*   deg    = (int*)alloc(sizeof(int) * NN);
  int*   excl   = (int*)alloc(sizeof(int) * NN);
  int*   bsum   = (int*)alloc(sizeof(int) * 64);
  int*   rowptr = (int*)alloc(sizeof(int) * (NN + 1));
  int*   wp     = (int*)alloc(sizeof(int) * NN);
  int*   root   = (int*)alloc(sizeof(int) * GG);
  int*   eidx   = (int*)alloc(sizeof(int) * EE);
  unsigned short* WT   = (unsigned short*)alloc(sizeof(short) * 6 * 128 * 128);
  unsigned short* xb   = (unsigned short*)alloc(sizeof(short) * NN * HH);
  unsigned short* aggb = (unsigned short*)alloc(sizeof(short) * NN * HH);
  unsigned short* h1   = (unsigned short*)alloc(sizeof(short) * NN * HH);
  unsigned short* h2   = (unsigned short*)alloc(sizeof(short) * NN * HH);
  float* hg = (float*)alloc(sizeof(float) * GG * HH);
  (void)ws_size; (void)n_in; (void)in_sizes; (void)out_size;

  zc_k<<<1, 1024, 0, stream>>>(bar);
  mega_k<<<NB, NT, 0, stream>>>(
      x, srcp, dstp, batch,
      W1l, b1l, W1r, W2l, b2l, W2r, W3l, b3l, W3r,
      Wnews, bnews, Wlin2, blin2, Wlin3, blin3,
      bar, deg, excl, bsum, rowptr, wp, root, eidx,
      WT, xb, aggb, h1, h2, hg, out);
}

// Round 9
// 217.101 us; speedup vs baseline: 3.6594x; 3.6594x over previous
//
#include <hip/hip_runtime.h>
#include <math.h>

#define NN 50000
#define EE 600000
#define GG 250
#define HH 128

// prep_k grid split
#define B_CVT  6250
#define B_W    384
#define B_ROOT 196
#define B_ZD   196
#define B_ZH   125

typedef __attribute__((ext_vector_type(8))) short s16x8;
typedef __attribute__((ext_vector_type(8))) unsigned short u16x8;
typedef __attribute__((ext_vector_type(4))) unsigned short u16x4;
typedef __attribute__((ext_vector_type(4))) float f32x4;

__device__ __forceinline__ float b2f(unsigned short u) {
  union { unsigned int i; float f; } v; v.i = ((unsigned int)u) << 16; return v.f;
}
__device__ __forceinline__ unsigned short f2b(float f) {
  union { float f; unsigned int i; } v; v.f = f;
  unsigned int x = v.i;
  unsigned int r = (x + 0x7FFFu + ((x >> 16) & 1u)) >> 16;   // RNE, finite inputs
  return (unsigned short)r;
}

// ---------- fused prep: cvt_x | cvtW | root | zero-deg | zero-hg ----------
__global__ __launch_bounds__(256) void prep_k(
    const float* __restrict__ x, unsigned short* __restrict__ xb,
    const float* __restrict__ W0, const float* __restrict__ W1,
    const float* __restrict__ W2, const float* __restrict__ W3,
    const float* __restrict__ W4, const float* __restrict__ W5,
    unsigned short* __restrict__ WT,
    int* __restrict__ deg,
    const int* __restrict__ batch, int* __restrict__ root,
    float* __restrict__ hg) {
  int b = blockIdx.x, tid = threadIdx.x;
  if (b < B_CVT) {
    int i = b * 256 + tid;                       // x4 floats
    float4 v = *(const float4*)&x[i * 4];
    u16x4 o; o[0] = f2b(v.x); o[1] = f2b(v.y); o[2] = f2b(v.z); o[3] = f2b(v.w);
    *(u16x4*)&xb[i * 4] = o;
  } else if (b < B_CVT + B_W) {
    int bb = b - B_CVT;
    int w = bb >> 6;
    const float* W = (w == 0) ? W0 : (w == 1) ? W1 : (w == 2) ? W2
                     : (w == 3) ? W3 : (w == 4) ? W4 : W5;
    int idx = (bb & 63) * 256 + tid;
    int j = idx >> 7, k = idx & 127;
    WT[w * 16384 + j * 128 + k] = f2b(W[k * 128 + j]);   // WT[col][k]
  } else if (b < B_CVT + B_W + B_ROOT) {
    int n = (b - B_CVT - B_W) * 256 + tid;
    if (n < NN) {
      int bg = batch[n];
      if (n == 0 || batch[n - 1] != bg) root[bg] = n;
    }
  } else if (b < B_CVT + B_W + B_ROOT + B_ZD) {
    int n = (b - B_CVT - B_W - B_ROOT) * 256 + tid;
    if (n < NN) deg[n] = 0;
  } else {
    int i = (b - B_CVT - B_W - B_ROOT - B_ZD) * 256 + tid;   // < 32000
    hg[i] = 0.f;
  }
}

// ---------- histogram (after deg zeroed in prep) ----------
__global__ void hist_k(const int* __restrict__ dst, int* __restrict__ deg) {
  int e = blockIdx.x * 256 + threadIdx.x;
  if (e < EE) atomicAdd(&deg[dst[e]], 1);
}

// ---------- scan, phase 1 ----------
__global__ __launch_bounds__(1024) void scan1_k(const int* __restrict__ deg,
                                                int* __restrict__ excl,
                                                int* __restrict__ bsum) {
  __shared__ int sums[16];
  int tid = threadIdx.x;
  int i = blockIdx.x * 1024 + tid;
  int v = (i < NN) ? deg[i] : 0;
  int lane = tid & 63, wid = tid >> 6;
  int x = v;
  #pragma unroll
  for (int d = 1; d < 64; d <<= 1) { int y = __shfl_up(x, d); if (lane >= d) x += y; }
  if (lane == 63) sums[wid] = x;
  __syncthreads();
  if (wid == 0) {
    int s = (lane < 16) ? sums[lane] : 0;
    #pragma unroll
    for (int d = 1; d < 16; d <<= 1) { int y = __shfl_up(s, d); if (lane >= d) s += y; }
    if (lane < 16) sums[lane] = s;
  }
  __syncthreads();
  int ex = (wid ? sums[wid - 1] : 0) + x - v;
  if (i < NN) excl[i] = ex;
  if (tid == 1023) bsum[blockIdx.x] = sums[15];
}

// ---------- scan, phase 2+3 fused ----------
__global__ __launch_bounds__(256) void scanB_k(const int* __restrict__ excl,
                                               const int* __restrict__ bsum,
                                               int* __restrict__ rowptr,
                                               int* __restrict__ wp) {
  __shared__ int sboff[64];
  int tid = threadIdx.x;
  if (tid < 64) {
    int v = (tid < 49) ? bsum[tid] : 0;
    int x = v;
    #pragma unroll
    for (int d = 1; d < 64; d <<= 1) { int y = __shfl_up(x, d); if (tid >= d) x += y; }
    sboff[tid] = x - v;
  }
  __syncthreads();
  int i = blockIdx.x * 256 + tid;
  if (i < NN) {
    int r = excl[i] + sboff[i >> 10];
    rowptr[i] = r; wp[i] = r;
  }
  if (i == 0) rowptr[NN] = EE;
}

__global__ void scatter_k(const int* __restrict__ src, const int* __restrict__ dst,
                          int* __restrict__ wp, int* __restrict__ eidx) {
  int e = blockIdx.x * 256 + threadIdx.x;
  if (e < EE) {
    int p = atomicAdd(&wp[dst[e]], 1);
    eidx[p] = src[e];
  }
}

// ---------- mean aggregation: 16 lanes/node, 8 unconditional row-loads in flight ----------
__global__ __launch_bounds__(256) void agg_k(const unsigned short* __restrict__ hb,
                                             const int* __restrict__ rowptr,
                                             const int* __restrict__ eidx,
                                             unsigned short* __restrict__ aggb) {
  int lane = threadIdx.x & 63, wid = threadIdx.x >> 6;
  int sub = lane >> 4, l16 = lane & 15;
  int base = sub * 16;                       // group's base lane in wave
  int node = blockIdx.x * 16 + wid * 4 + sub;
  int start = rowptr[node], end = rowptr[node + 1];
  float acc[8] = {0.f, 0.f, 0.f, 0.f, 0.f, 0.f, 0.f, 0.f};
  for (int c = start; c < end; c += 8) {
    // one coalesced eidx load covers 8 edges (lanes 8-15 mirror 0-7)
    int ecl = c + (l16 & 7); if (ecl > end - 1) ecl = end - 1;
    int myidx = eidx[ecl];
    int s[8];
    #pragma unroll
    for (int t = 0; t < 8; ++t) s[t] = __shfl(myidx, base + t);
    u16x8 rv[8];
    #pragma unroll
    for (int t = 0; t < 8; ++t)
      rv[t] = *(const u16x8*)&hb[s[t] * HH + l16 * 8];   // always issued, clamped idx
    #pragma unroll
    for (int t = 0; t < 8; ++t) {
      if (c + t < end) {
        #pragma unroll
        for (int j = 0; j < 8; ++j) acc[j] += b2f(rv[t][j]);
      }
    }
  }
  int cnt = end - start;
  float inv = 1.f / (float)(cnt > 0 ? cnt : 1);
  u16x8 o;
  #pragma unroll
  for (int j = 0; j < 8; ++j) o[j] = f2b(acc[j] * inv);
  *(u16x8*)&aggb[node * HH + l16 * 8] = o;
}

// ---------- MFMA sage layer, LDS-staged weights ----------
// WlT points at 64KB of [Wl^T ; Wr^T] (contiguous). Block = 128 rows, 4 waves,
// each wave 2 row-tiles of 16 so every B-fragment ds_read feeds 2 MFMAs.
__global__ __launch_bounds__(256) void sage_k(
    const unsigned short* __restrict__ aggb, const unsigned short* __restrict__ hb,
    const unsigned short* __restrict__ WlT, const float* __restrict__ bl,
    unsigned short* __restrict__ hout, float* __restrict__ hgmax) {
  __shared__ unsigned short sW[32768];   // 64 KB: [0..16383]=Wl^T, [16384..]=Wr^T
  int tid = threadIdx.x;
  int lane = tid & 63, wid = tid >> 6;
  int l16 = lane & 15, hi = lane >> 4;
  int rbase = blockIdx.x * 128 + wid * 32;

  // A fragments first (issue-early: independent of LDS staging below)
  s16x8 aA[2][4], aH[2][4];
  #pragma unroll
  for (int rt = 0; rt < 2; ++rt) {
    int ar = rbase + rt * 16 + l16; if (ar > NN - 1) ar = NN - 1;
    #pragma unroll
    for (int kk = 0; kk < 4; ++kk) {
      aA[rt][kk] = *(const s16x8*)&aggb[ar * HH + kk * 32 + hi * 8];
      aH[rt][kk] = *(const s16x8*)&hb[ar * HH + kk * 32 + hi * 8];
    }
  }

  // stage both weight matrices, 16B-unit XOR swizzle (unit ^ row&7) -> 2-way banks
  #pragma unroll
  for (int i = 0; i < 16; ++i) {
    int u = i * 256 + tid;
    int row = u >> 4, unit = u & 15;
    u16x8 w = *(const u16x8*)&WlT[row * 128 + unit * 8];
    *(u16x8*)&sW[row * 128 + ((unit ^ (row & 7)) * 8)] = w;
  }
  __syncthreads();

  f32x4 acc[2][8];
  #pragma unroll
  for (int rt = 0; rt < 2; ++rt)
    #pragma unroll
    for (int cc = 0; cc < 8; ++cc) acc[rt][cc] = (f32x4){0.f, 0.f, 0.f, 0.f};

  #pragma unroll
  for (int cc = 0; cc < 8; ++cc) {
    int brow = cc * 16 + l16;
    int bb = brow * 128;
    int sw = brow & 7;
    #pragma unroll
    for (int kk = 0; kk < 4; ++kk) {
      int un = (kk * 4 + hi) ^ sw;
      s16x8 bL = *(const s16x8*)&sW[bb + un * 8];
      acc[0][cc] = __builtin_amdgcn_mfma_f32_16x16x32_bf16(aA[0][kk], bL, acc[0][cc], 0, 0, 0);
      acc[1][cc] = __builtin_amdgcn_mfma_f32_16x16x32_bf16(aA[1][kk], bL, acc[1][cc], 0, 0, 0);
      s16x8 bR = *(const s16x8*)&sW[16384 + bb + un * 8];
      acc[0][cc] = __builtin_amdgcn_mfma_f32_16x16x32_bf16(aH[0][kk], bR, acc[0][cc], 0, 0, 0);
      acc[1][cc] = __builtin_amdgcn_mfma_f32_16x16x32_bf16(aH[1][kk], bR, acc[1][cc], 0, 0, 0);
    }
  }

  // epilogue per row-tile: bias, L2 norm, relu, store (+ fused max-pool layer 3)
  #pragma unroll
  for (int rt = 0; rt < 2; ++rt) {
    int rtb = rbase + rt * 16;
    float v[8][4];
    float ss[4] = {0.f, 0.f, 0.f, 0.f};
    #pragma unroll
    for (int cc = 0; cc < 8; ++cc) {
      float bb = bl[cc * 16 + l16];
      #pragma unroll
      for (int i = 0; i < 4; ++i) {
        float t = acc[rt][cc][i] + bb;
        v[cc][i] = t;
        ss[i] += t * t;
      }
    }
    #pragma unroll
    for (int m = 1; m < 16; m <<= 1) {
      #pragma unroll
      for (int i = 0; i < 4; ++i) ss[i] += __shfl_xor(ss[i], m);
    }
    float inv[4];
    #pragma unroll
    for (int i = 0; i < 4; ++i) inv[i] = 1.f / fmaxf(sqrtf(ss[i]), 1e-12f);
    #pragma unroll
    for (int cc = 0; cc < 8; ++cc) {
      #pragma unroll
      for (int i = 0; i < 4; ++i) {
        int row = rtb + hi * 4 + i;
        if (row < NN)
          hout[row * HH + cc * 16 + l16] = f2b(fmaxf(v[cc][i] * inv[i], 0.f));
      }
    }
    if (hgmax) {
      int r4 = rtb + hi * 4;
      if (r4 < NN) {
        int g = r4 / 200;                    // 4-row strips never cross graphs
        #pragma unroll
        for (int cc = 0; cc < 8; ++cc) {
          float vm = 0.f;                    // relu floor
          #pragma unroll
          for (int i = 0; i < 4; ++i)
            if (r4 + i < NN) vm = fmaxf(vm, fmaxf(v[cc][i] * inv[i], 0.f));
          atomicMax((int*)&hgmax[g * HH + cc * 16 + l16], __float_as_int(vm));
        }
      }
    }
  }
}

// ---------- final: news + lin2 + lin3 + sigmoid (hg from fused pool) ----------
__global__ __launch_bounds__(128) void final_k(
    const float* __restrict__ hg, const int* __restrict__ root,
    const float* __restrict__ x,
    const float* __restrict__ Wn, const float* __restrict__ bn,
    const float* __restrict__ W2, const float* __restrict__ b2,
    const float* __restrict__ W3, const float* __restrict__ b3,
    float* __restrict__ out) {
  __shared__ float hgr[128];
  __shared__ float xr[128];
  __shared__ float red[2];
  int g = blockIdx.x, j = threadIdx.x;
  int rt = root[g];
  hgr[j] = hg[g * HH + j];
  xr[j] = x[rt * HH + j];
  __syncthreads();
  float acc2 = b2[j];
  float accn = bn[j];
  for (int k = 0; k < 128; ++k) {
    acc2 += hgr[k] * W2[k * HH + j];
    accn += xr[k] * Wn[k * HH + j];
  }
  float c = fmaxf(acc2, 0.f) * W3[j] + fmaxf(accn, 0.f) * W3[HH + j];
  #pragma unroll
  for (int d = 1; d < 64; d <<= 1) c += __shfl_xor(c, d);
  if ((j & 63) == 0) red[j >> 6] = c;
  __syncthreads();
  if (j == 0) out[g] = 1.f / (1.f + expf(-(red[0] + red[1] + b3[0])));
}

extern "C" void kernel_launch(void* const* d_in, const int* in_sizes, int n_in,
                              void* d_out, int out_size, void* d_ws, size_t ws_size,
                              hipStream_t stream) {
  const float* x     = (const float*)d_in[0];
  const int*   adj   = (const int*)d_in[1];
  const int*   batch = (const int*)d_in[2];
  const float *W1l = (const float*)d_in[3],  *b1l = (const float*)d_in[4],  *W1r = (const float*)d_in[5];
  const float *W2l = (const float*)d_in[6],  *b2l = (const float*)d_in[7],  *W2r = (const float*)d_in[8];
  const float *W3l = (const float*)d_in[9],  *b3l = (const float*)d_in[10], *W3r = (const float*)d_in[11];
  const float *Wnews = (const float*)d_in[12], *bnews = (const float*)d_in[13];
  const float *Wlin2 = (const float*)d_in[14], *blin2 = (const float*)d_in[15];
  const float *Wlin3 = (const float*)d_in[16], *blin3 = (const float*)d_in[17];
  float* out = (float*)d_out;

  const int* srcp = adj;
  const int* dstp = adj + EE;

  char* ws = (char*)d_ws;
  size_t off = 0;
  auto alloc = [&](size_t bytes) -> void* {
    void* p = ws + off;
    off = (off + bytes + 255) & ~(size_t)255;
    return p;
  };
  int*   deg    = (int*)alloc(sizeof(int) * NN);
  int*   excl   = (int*)alloc(sizeof(int) * NN);
  int*   bsum   = (int*)alloc(sizeof(int) * 64);
  int*   rowptr = (int*)alloc(sizeof(int) * (NN + 1));
  int*   wp     = (int*)alloc(sizeof(int) * NN);
  int*   root   = (int*)alloc(sizeof(int) * GG);
  int*   eidx   = (int*)alloc(sizeof(int) * EE);
  unsigned short* WT   = (unsigned short*)alloc(sizeof(short) * 6 * 128 * 128);
  unsigned short* xb   = (unsigned short*)alloc(sizeof(short) * NN * HH);
  unsigned short* aggb = (unsigned short*)alloc(sizeof(short) * NN * HH);
  unsigned short* h1   = (unsigned short*)alloc(sizeof(short) * NN * HH);
  unsigned short* h2   = (unsigned short*)alloc(sizeof(short) * NN * HH);
  float* hg = (float*)alloc(sizeof(float) * GG * HH);
  (void)ws_size; (void)n_in; (void)in_sizes; (void)out_size;

  prep_k<<<B_CVT + B_W + B_ROOT + B_ZD + B_ZH, 256, 0, stream>>>(
      x, xb, W1l, W1r, W2l, W2r, W3l, W3r, WT, deg, batch, root, hg);
  hist_k<<<(EE + 255) / 256, 256, 0, stream>>>(dstp, deg);
  scan1_k<<<(NN + 1023) / 1024, 1024, 0, stream>>>(deg, excl, bsum);
  scanB_k<<<(NN + 255) / 256, 256, 0, stream>>>(excl, bsum, rowptr, wp);
  scatter_k<<<(EE + 255) / 256, 256, 0, stream>>>(srcp, dstp, wp, eidx);

  const int AGG_GRID = NN / 16;              // 3125
  const int GEMM_GRID = (NN + 127) / 128;    // 391

  agg_k<<<AGG_GRID, 256, 0, stream>>>(xb, rowptr, eidx, aggb);
  sage_k<<<GEMM_GRID, 256, 0, stream>>>(aggb, xb, WT + 0 * 16384, b1l, h1, nullptr);
  agg_k<<<AGG_GRID, 256, 0, stream>>>(h1, rowptr, eidx, aggb);
  sage_k<<<GEMM_GRID, 256, 0, stream>>>(aggb, h1, WT + 2 * 16384, b2l, h2, nullptr);
  agg_k<<<AGG_GRID, 256, 0, stream>>>(h2, rowptr, eidx, aggb);
  sage_k<<<GEMM_GRID, 256, 0, stream>>>(aggb, h2, WT + 4 * 16384, b3l, h1, hg);

  final_k<<<GG, 128, 0, stream>>>(hg, root, x, Wnews, bnews,
                                  Wlin2, blin2, Wlin3, blin3, out);
}

// Round 10
// 210.575 us; speedup vs baseline: 3.7728x; 1.0310x over previous
//
#include <hip/hip_runtime.h>
#include <math.h>

#define NN 50000
#define EE 600000
#define GG 250
#define HH 128

// prep_k grid split
#define B_CVT  6250
#define B_W    384
#define B_ROOT 196
#define B_ZD   196
#define B_ZH   125

typedef __attribute__((ext_vector_type(8))) short s16x8;
typedef __attribute__((ext_vector_type(8))) unsigned short u16x8;
typedef __attribute__((ext_vector_type(4))) unsigned short u16x4;
typedef __attribute__((ext_vector_type(4))) float f32x4;

__device__ __forceinline__ float b2f(unsigned short u) {
  union { unsigned int i; float f; } v; v.i = ((unsigned int)u) << 16; return v.f;
}
__device__ __forceinline__ unsigned short f2b(float f) {
  union { float f; unsigned int i; } v; v.f = f;
  unsigned int x = v.i;
  unsigned int r = (x + 0x7FFFu + ((x >> 16) & 1u)) >> 16;   // RNE, finite inputs
  return (unsigned short)r;
}

// ---------- fused prep: cvt_x | cvtW | root | zero-deg | zero-hg ----------
__global__ __launch_bounds__(256) void prep_k(
    const float* __restrict__ x, unsigned short* __restrict__ xb,
    const float* __restrict__ W0, const float* __restrict__ W1,
    const float* __restrict__ W2, const float* __restrict__ W3,
    const float* __restrict__ W4, const float* __restrict__ W5,
    unsigned short* __restrict__ WT,
    int* __restrict__ deg,
    const int* __restrict__ batch, int* __restrict__ root,
    float* __restrict__ hg) {
  int b = blockIdx.x, tid = threadIdx.x;
  if (b < B_CVT) {
    int i = b * 256 + tid;                       // x4 floats
    float4 v = *(const float4*)&x[i * 4];
    u16x4 o; o[0] = f2b(v.x); o[1] = f2b(v.y); o[2] = f2b(v.z); o[3] = f2b(v.w);
    *(u16x4*)&xb[i * 4] = o;
  } else if (b < B_CVT + B_W) {
    int bb = b - B_CVT;
    int w = bb >> 6;
    const float* W = (w == 0) ? W0 : (w == 1) ? W1 : (w == 2) ? W2
                     : (w == 3) ? W3 : (w == 4) ? W4 : W5;
    int idx = (bb & 63) * 256 + tid;
    int j = idx >> 7, k = idx & 127;
    WT[w * 16384 + j * 128 + k] = f2b(W[k * 128 + j]);   // WT[col][k]
  } else if (b < B_CVT + B_W + B_ROOT) {
    int n = (b - B_CVT - B_W) * 256 + tid;
    if (n < NN) {
      int bg = batch[n];
      if (n == 0 || batch[n - 1] != bg) root[bg] = n;
    }
  } else if (b < B_CVT + B_W + B_ROOT + B_ZD) {
    int n = (b - B_CVT - B_W - B_ROOT) * 256 + tid;
    if (n < NN) deg[n] = 0;
  } else {
    int i = (b - B_CVT - B_W - B_ROOT - B_ZD) * 256 + tid;   // < 32000
    hg[i] = 0.f;
  }
}

// ---------- histogram (after deg zeroed in prep) ----------
__global__ void hist_k(const int* __restrict__ dst, int* __restrict__ deg) {
  int e = blockIdx.x * 256 + threadIdx.x;
  if (e < EE) atomicAdd(&deg[dst[e]], 1);
}

// ---------- scan, phase 1 ----------
__global__ __launch_bounds__(1024) void scan1_k(const int* __restrict__ deg,
                                                int* __restrict__ excl,
                                                int* __restrict__ bsum) {
  __shared__ int sums[16];
  int tid = threadIdx.x;
  int i = blockIdx.x * 1024 + tid;
  int v = (i < NN) ? deg[i] : 0;
  int lane = tid & 63, wid = tid >> 6;
  int x = v;
  #pragma unroll
  for (int d = 1; d < 64; d <<= 1) { int y = __shfl_up(x, d); if (lane >= d) x += y; }
  if (lane == 63) sums[wid] = x;
  __syncthreads();
  if (wid == 0) {
    int s = (lane < 16) ? sums[lane] : 0;
    #pragma unroll
    for (int d = 1; d < 16; d <<= 1) { int y = __shfl_up(s, d); if (lane >= d) s += y; }
    if (lane < 16) sums[lane] = s;
  }
  __syncthreads();
  int ex = (wid ? sums[wid - 1] : 0) + x - v;
  if (i < NN) excl[i] = ex;
  if (tid == 1023) bsum[blockIdx.x] = sums[15];
}

// ---------- scan, phase 2+3 fused ----------
__global__ __launch_bounds__(256) void scanB_k(const int* __restrict__ excl,
                                               const int* __restrict__ bsum,
                                               int* __restrict__ rowptr,
                                               int* __restrict__ wp) {
  __shared__ int sboff[64];
  int tid = threadIdx.x;
  if (tid < 64) {
    int v = (tid < 49) ? bsum[tid] : 0;
    int x = v;
    #pragma unroll
    for (int d = 1; d < 64; d <<= 1) { int y = __shfl_up(x, d); if (tid >= d) x += y; }
    sboff[tid] = x - v;
  }
  __syncthreads();
  int i = blockIdx.x * 256 + tid;
  if (i < NN) {
    int r = excl[i] + sboff[i >> 10];
    rowptr[i] = r; wp[i] = r;
  }
  if (i == 0) rowptr[NN] = EE;
}

__global__ void scatter_k(const int* __restrict__ src, const int* __restrict__ dst,
                          int* __restrict__ wp, int* __restrict__ eidx) {
  int e = blockIdx.x * 256 + threadIdx.x;
  if (e < EE) {
    int p = atomicAdd(&wp[dst[e]], 1);
    eidx[p] = src[e];
  }
}

// ---------- mean aggregation: 16 lanes/node, 8 unconditional row-loads in flight ----------
__global__ __launch_bounds__(256) void agg_k(const unsigned short* __restrict__ hb,
                                             const int* __restrict__ rowptr,
                                             const int* __restrict__ eidx,
                                             unsigned short* __restrict__ aggb) {
  int lane = threadIdx.x & 63, wid = threadIdx.x >> 6;
  int sub = lane >> 4, l16 = lane & 15;
  int base = sub * 16;                       // group's base lane in wave
  int node = blockIdx.x * 16 + wid * 4 + sub;
  int start = rowptr[node], end = rowptr[node + 1];
  float acc[8] = {0.f, 0.f, 0.f, 0.f, 0.f, 0.f, 0.f, 0.f};
  for (int c = start; c < end; c += 8) {
    // one coalesced eidx load covers 8 edges (lanes 8-15 mirror 0-7)
    int ecl = c + (l16 & 7); if (ecl > end - 1) ecl = end - 1;
    int myidx = eidx[ecl];
    int s[8];
    #pragma unroll
    for (int t = 0; t < 8; ++t) s[t] = __shfl(myidx, base + t);
    u16x8 rv[8];
    #pragma unroll
    for (int t = 0; t < 8; ++t)
      rv[t] = *(const u16x8*)&hb[s[t] * HH + l16 * 8];   // always issued, clamped idx
    #pragma unroll
    for (int t = 0; t < 8; ++t) {
      if (c + t < end) {
        #pragma unroll
        for (int j = 0; j < 8; ++j) acc[j] += b2f(rv[t][j]);
      }
    }
  }
  int cnt = end - start;
  float inv = 1.f / (float)(cnt > 0 ? cnt : 1);
  u16x8 o;
  #pragma unroll
  for (int j = 0; j < 8; ++j) o[j] = f2b(acc[j] * inv);
  *(u16x8*)&aggb[node * HH + l16 * 8] = o;
}

// ---------- MFMA sage layer v4: register-stationary weights + LDS A-tiles ----------
// Each wave owns 2 of the 8 output col-tiles (B-frags in 64 VGPRs, loaded once).
// A-tiles (16 rows of aggb & hb) are staged coalesced into 8KB LDS per tile,
// XOR-swizzled, fragments read via conflict-free ds_read_b128.
// 625 blocks x 5 tiles = 3125 tiles x 16 rows = 50000 exactly (no guards).
__global__ __launch_bounds__(256, 3) void sage_k(
    const unsigned short* __restrict__ aggb, const unsigned short* __restrict__ hb,
    const unsigned short* __restrict__ WlT, const float* __restrict__ bl,
    unsigned short* __restrict__ hout, float* __restrict__ hgmax) {
  __shared__ unsigned short sA[16 * 128];   // 4KB
  __shared__ unsigned short sH[16 * 128];   // 4KB
  __shared__ float sred[4][16];
  int tid = threadIdx.x;
  int lane = tid & 63, wid = tid >> 6;
  int l16 = lane & 15, hi = lane >> 4;
  int cc0 = wid * 2;                        // this wave's 2 col-tiles

  // weights in registers: 2cc x 4kk x {Wl,Wr} = 16 frags = 64 VGPRs
  s16x8 wl[2][4], wr[2][4];
  #pragma unroll
  for (int c = 0; c < 2; ++c) {
    int brow = (cc0 + c) * 16 + l16;
    #pragma unroll
    for (int kk = 0; kk < 4; ++kk) {
      wl[c][kk] = *(const s16x8*)&WlT[brow * 128 + kk * 32 + hi * 8];
      wr[c][kk] = *(const s16x8*)&WlT[16384 + brow * 128 + kk * 32 + hi * 8];
    }
  }
  float bb[2] = { bl[cc0 * 16 + l16], bl[(cc0 + 1) * 16 + l16] };

  int srow = tid >> 4, sunit = tid & 15;    // staging: thread -> (row, 16B-unit)
  int sdst = srow * 128 + ((sunit ^ (srow & 7)) * 8);

  for (int t = 0; t < 5; ++t) {
    int r0 = (blockIdx.x * 5 + t) * 16;
    // coalesced 4KB loads (tid*16B contiguous)
    u16x8 va = *(const u16x8*)&aggb[r0 * 128 + tid * 8];
    u16x8 vh = *(const u16x8*)&hb[r0 * 128 + tid * 8];
    *(u16x8*)&sA[sdst] = va;
    *(u16x8*)&sH[sdst] = vh;
    __syncthreads();

    f32x4 acc[2];
    acc[0] = (f32x4){0.f, 0.f, 0.f, 0.f};
    acc[1] = (f32x4){0.f, 0.f, 0.f, 0.f};
    #pragma unroll
    for (int kk = 0; kk < 4; ++kk) {
      int un = (((kk * 4 + hi) ^ (l16 & 7)) * 8);
      s16x8 a = *(const s16x8*)&sA[l16 * 128 + un];
      s16x8 h = *(const s16x8*)&sH[l16 * 128 + un];
      acc[0] = __builtin_amdgcn_mfma_f32_16x16x32_bf16(a, wl[0][kk], acc[0], 0, 0, 0);
      acc[0] = __builtin_amdgcn_mfma_f32_16x16x32_bf16(h, wr[0][kk], acc[0], 0, 0, 0);
      acc[1] = __builtin_amdgcn_mfma_f32_16x16x32_bf16(a, wl[1][kk], acc[1], 0, 0, 0);
      acc[1] = __builtin_amdgcn_mfma_f32_16x16x32_bf16(h, wr[1][kk], acc[1], 0, 0, 0);
    }

    // epilogue: bias, partial norm over this wave's 32 cols, cross-wave combine
    float v[2][4];
    float ss[4] = {0.f, 0.f, 0.f, 0.f};
    #pragma unroll
    for (int c = 0; c < 2; ++c) {
      #pragma unroll
      for (int i = 0; i < 4; ++i) {
        float tv = acc[c][i] + bb[c];
        v[c][i] = tv;
        ss[i] += tv * tv;
      }
    }
    #pragma unroll
    for (int m = 1; m < 16; m <<= 1) {
      #pragma unroll
      for (int i = 0; i < 4; ++i) ss[i] += __shfl_xor(ss[i], m);
    }
    if (l16 == 0) {
      #pragma unroll
      for (int i = 0; i < 4; ++i) sred[wid][hi * 4 + i] = ss[i];
    }
    __syncthreads();
    float inv[4];
    #pragma unroll
    for (int i = 0; i < 4; ++i) {
      int r = hi * 4 + i;
      float s = sred[0][r] + sred[1][r] + sred[2][r] + sred[3][r];
      inv[i] = 1.f / fmaxf(sqrtf(s), 1e-12f);
    }
    #pragma unroll
    for (int c = 0; c < 2; ++c) {
      #pragma unroll
      for (int i = 0; i < 4; ++i) {
        int row = r0 + hi * 4 + i;
        hout[row * HH + (cc0 + c) * 16 + l16] = f2b(fmaxf(v[c][i] * inv[i], 0.f));
      }
    }
    if (hgmax) {
      int g = (r0 + hi * 4) / 200;          // 4-row strips never cross graphs
      #pragma unroll
      for (int c = 0; c < 2; ++c) {
        float vm = 0.f;                     // relu floor
        #pragma unroll
        for (int i = 0; i < 4; ++i) vm = fmaxf(vm, fmaxf(v[c][i] * inv[i], 0.f));
        atomicMax((int*)&hgmax[g * HH + (cc0 + c) * 16 + l16], __float_as_int(vm));
      }
    }
    __syncthreads();                        // sA/sH + sred reuse guard for next tile
  }
}

// ---------- final: news + lin2 + lin3 + sigmoid (hg from fused pool) ----------
__global__ __launch_bounds__(128) void final_k(
    const float* __restrict__ hg, const int* __restrict__ root,
    const float* __restrict__ x,
    const float* __restrict__ Wn, const float* __restrict__ bn,
    const float* __restrict__ W2, const float* __restrict__ b2,
    const float* __restrict__ W3, const float* __restrict__ b3,
    float* __restrict__ out) {
  __shared__ float hgr[128];
  __shared__ float xr[128];
  __shared__ float red[2];
  int g = blockIdx.x, j = threadIdx.x;
  int rt = root[g];
  hgr[j] = hg[g * HH + j];
  xr[j] = x[rt * HH + j];
  __syncthreads();
  float acc2 = b2[j];
  float accn = bn[j];
  for (int k = 0; k < 128; ++k) {
    acc2 += hgr[k] * W2[k * HH + j];
    accn += xr[k] * Wn[k * HH + j];
  }
  float c = fmaxf(acc2, 0.f) * W3[j] + fmaxf(accn, 0.f) * W3[HH + j];
  #pragma unroll
  for (int d = 1; d < 64; d <<= 1) c += __shfl_xor(c, d);
  if ((j & 63) == 0) red[j >> 6] = c;
  __syncthreads();
  if (j == 0) out[g] = 1.f / (1.f + expf(-(red[0] + red[1] + b3[0])));
}

extern "C" void kernel_launch(void* const* d_in, const int* in_sizes, int n_in,
                              void* d_out, int out_size, void* d_ws, size_t ws_size,
                              hipStream_t stream) {
  const float* x     = (const float*)d_in[0];
  const int*   adj   = (const int*)d_in[1];
  const int*   batch = (const int*)d_in[2];
  const float *W1l = (const float*)d_in[3],  *b1l = (const float*)d_in[4],  *W1r = (const float*)d_in[5];
  const float *W2l = (const float*)d_in[6],  *b2l = (const float*)d_in[7],  *W2r = (const float*)d_in[8];
  const float *W3l = (const float*)d_in[9],  *b3l = (const float*)d_in[10], *W3r = (const float*)d_in[11];
  const float *Wnews = (const float*)d_in[12], *bnews = (const float*)d_in[13];
  const float *Wlin2 = (const float*)d_in[14], *blin2 = (const float*)d_in[15];
  const float *Wlin3 = (const float*)d_in[16], *blin3 = (const float*)d_in[17];
  float* out = (float*)d_out;

  const int* srcp = adj;
  const int* dstp = adj + EE;

  char* ws = (char*)d_ws;
  size_t off = 0;
  auto alloc = [&](size_t bytes) -> void* {
    void* p = ws + off;
    off = (off + bytes + 255) & ~(size_t)255;
    return p;
  };
  int*   deg    = (int*)alloc(sizeof(int) * NN);
  int*   excl   = (int*)alloc(sizeof(int) * NN);
  int*   bsum   = (int*)alloc(sizeof(int) * 64);
  int*   rowptr = (int*)alloc(sizeof(int) * (NN + 1));
  int*   wp     = (int*)alloc(sizeof(int) * NN);
  int*   root   = (int*)alloc(sizeof(int) * GG);
  int*   eidx   = (int*)alloc(sizeof(int) * EE);
  unsigned short* WT   = (unsigned short*)alloc(sizeof(short) * 6 * 128 * 128);
  unsigned short* xb   = (unsigned short*)alloc(sizeof(short) * NN * HH);
  unsigned short* aggb = (unsigned short*)alloc(sizeof(short) * NN * HH);
  unsigned short* h1   = (unsigned short*)alloc(sizeof(short) * NN * HH);
  unsigned short* h2   = (unsigned short*)alloc(sizeof(short) * NN * HH);
  float* hg = (float*)alloc(sizeof(float) * GG * HH);
  (void)ws_size; (void)n_in; (void)in_sizes; (void)out_size;

  prep_k<<<B_CVT + B_W + B_ROOT + B_ZD + B_ZH, 256, 0, stream>>>(
      x, xb, W1l, W1r, W2l, W2r, W3l, W3r, WT, deg, batch, root, hg);
  hist_k<<<(EE + 255) / 256, 256, 0, stream>>>(dstp, deg);
  scan1_k<<<(NN + 1023) / 1024, 1024, 0, stream>>>(deg, excl, bsum);
  scanB_k<<<(NN + 255) / 256, 256, 0, stream>>>(excl, bsum, rowptr, wp);
  scatter_k<<<(EE + 255) / 256, 256, 0, stream>>>(srcp, dstp, wp, eidx);

  const int AGG_GRID = NN / 16;              // 3125
  const int GEMM_GRID = 625;                 // x5 tiles of 16 rows = 50000

  agg_k<<<AGG_GRID, 256, 0, stream>>>(xb, rowptr, eidx, aggb);
  sage_k<<<GEMM_GRID, 256, 0, stream>>>(aggb, xb, WT + 0 * 16384, b1l, h1, nullptr);
  agg_k<<<AGG_GRID, 256, 0, stream>>>(h1, rowptr, eidx, aggb);
  sage_k<<<GEMM_GRID, 256, 0, stream>>>(aggb, h1, WT + 2 * 16384, b2l, h2, nullptr);
  agg_k<<<AGG_GRID, 256, 0, stream>>>(h2, rowptr, eidx, aggb);
  sage_k<<<GEMM_GRID, 256, 0, stream>>>(aggb, h2, WT + 4 * 16384, b3l, h1, hg);

  final_k<<<GG, 128, 0, stream>>>(hg, root, x, Wnews, bnews,
                                  Wlin2, blin2, Wlin3, blin3, out);
}

// Round 12
// 203.845 us; speedup vs baseline: 3.8974x; 1.0330x over previous
//
#include <hip/hip_runtime.h>
#include <math.h>

#define NN 50000
#define EE 600000
#define GG 250
#define HH 128

// prep_k grid split
#define B_CVT  6250
#define B_W    384
#define B_ROOT 196
#define B_ZD   196
#define B_ZH   125

typedef __attribute__((ext_vector_type(8))) short s16x8;
typedef __attribute__((ext_vector_type(8))) unsigned short u16x8;
typedef __attribute__((ext_vector_type(4))) unsigned short u16x4;
typedef __attribute__((ext_vector_type(4))) float f32x4;

__device__ __forceinline__ float b2f(unsigned short u) {
  union { unsigned int i; float f; } v; v.i = ((unsigned int)u) << 16; return v.f;
}
__device__ __forceinline__ unsigned short f2b(float f) {
  union { float f; unsigned int i; } v; v.f = f;
  unsigned int x = v.i;
  unsigned int r = (x + 0x7FFFu + ((x >> 16) & 1u)) >> 16;   // RNE, finite inputs
  return (unsigned short)r;
}

// ---------- fused prep: cvt_x | cvtW(fragment layout) | root | zero-deg | zero-hg ----------
// WT2 layout: idx = L*32768 + w*4096 + m*2048 + kk*512 + lane*8 + j
//   holds W[L][m]^T fragment for col-tile cc=w: value W[k*128+col],
//   col = w*16 + (lane&15), k = kk*32 + ((lane>>4)&3)*8 + j.
// In-kernel weight loads are then 64 lanes x 16B = 1KB contiguous.
__global__ __launch_bounds__(256) void prep_k(
    const float* __restrict__ x, unsigned short* __restrict__ xb,
    const float* __restrict__ W0, const float* __restrict__ W1,
    const float* __restrict__ W2, const float* __restrict__ W3,
    const float* __restrict__ W4, const float* __restrict__ W5,
    unsigned short* __restrict__ WT,
    int* __restrict__ deg,
    const int* __restrict__ batch, int* __restrict__ root,
    float* __restrict__ hg) {
  int b = blockIdx.x, tid = threadIdx.x;
  if (b < B_CVT) {
    int i = b * 256 + tid;                       // x4 floats
    float4 v = *(const float4*)&x[i * 4];
    u16x4 o; o[0] = f2b(v.x); o[1] = f2b(v.y); o[2] = f2b(v.z); o[3] = f2b(v.w);
    *(u16x4*)&xb[i * 4] = o;
  } else if (b < B_CVT + B_W) {
    int i = (b - B_CVT) * 256 + tid;             // 0..98303
    int j = i & 7, lane = (i >> 3) & 63, kk = (i >> 9) & 3;
    int m = (i >> 11) & 1, w = (i >> 12) & 7, L = i >> 15;
    int sel = L * 2 + m;
    const float* W = (sel == 0) ? W0 : (sel == 1) ? W1 : (sel == 2) ? W2
                     : (sel == 3) ? W3 : (sel == 4) ? W4 : W5;
    int col = w * 16 + (lane & 15);
    int k = kk * 32 + ((lane >> 4) & 3) * 8 + j;
    WT[i] = f2b(W[k * 128 + col]);
  } else if (b < B_CVT + B_W + B_ROOT) {
    int n = (b - B_CVT - B_W) * 256 + tid;
    if (n < NN) {
      int bg = batch[n];
      if (n == 0 || batch[n - 1] != bg) root[bg] = n;
    }
  } else if (b < B_CVT + B_W + B_ROOT + B_ZD) {
    int n = (b - B_CVT - B_W - B_ROOT) * 256 + tid;
    if (n < NN) deg[n] = 0;
  } else {
    int i = (b - B_CVT - B_W - B_ROOT - B_ZD) * 256 + tid;   // < 32000
    hg[i] = 0.f;
  }
}

// ---------- histogram ----------
__global__ void hist_k(const int* __restrict__ dst, int* __restrict__ deg) {
  int e = blockIdx.x * 256 + threadIdx.x;
  if (e < EE) atomicAdd(&deg[dst[e]], 1);
}

// ---------- scan, phase 1 ----------
__global__ __launch_bounds__(1024) void scan1_k(const int* __restrict__ deg,
                                                int* __restrict__ excl,
                                                int* __restrict__ bsum) {
  __shared__ int sums[16];
  int tid = threadIdx.x;
  int i = blockIdx.x * 1024 + tid;
  int v = (i < NN) ? deg[i] : 0;
  int lane = tid & 63, wid = tid >> 6;
  int x = v;
  #pragma unroll
  for (int d = 1; d < 64; d <<= 1) { int y = __shfl_up(x, d); if (lane >= d) x += y; }
  if (lane == 63) sums[wid] = x;
  __syncthreads();
  if (wid == 0) {
    int s = (lane < 16) ? sums[lane] : 0;
    #pragma unroll
    for (int d = 1; d < 16; d <<= 1) { int y = __shfl_up(s, d); if (lane >= d) s += y; }
    if (lane < 16) sums[lane] = s;
  }
  __syncthreads();
  int ex = (wid ? sums[wid - 1] : 0) + x - v;
  if (i < NN) excl[i] = ex;
  if (tid == 1023) bsum[blockIdx.x] = sums[15];
}

// ---------- scan, phase 2+3 fused ----------
__global__ __launch_bounds__(256) void scanB_k(const int* __restrict__ excl,
                                               const int* __restrict__ bsum,
                                               int* __restrict__ rowptr,
                                               int* __restrict__ wp) {
  __shared__ int sboff[64];
  int tid = threadIdx.x;
  if (tid < 64) {
    int v = (tid < 49) ? bsum[tid] : 0;
    int x = v;
    #pragma unroll
    for (int d = 1; d < 64; d <<= 1) { int y = __shfl_up(x, d); if (tid >= d) x += y; }
    sboff[tid] = x - v;
  }
  __syncthreads();
  int i = blockIdx.x * 256 + tid;
  if (i < NN) {
    int r = excl[i] + sboff[i >> 10];
    rowptr[i] = r; wp[i] = r;
  }
  if (i == 0) rowptr[NN] = EE;
}

__global__ void scatter_k(const int* __restrict__ src, const int* __restrict__ dst,
                          int* __restrict__ wp, int* __restrict__ eidx) {
  int e = blockIdx.x * 256 + threadIdx.x;
  if (e < EE) {
    int p = atomicAdd(&wp[dst[e]], 1);
    eidx[p] = src[e];
  }
}

// ---------- fused layer: gather-mean -> LDS, MFMA, L2norm, relu, coalesced store ----------
// 512 threads / 8 waves / 64 rows per block. Wave w owns col-tile cc=w.
// Weights: 8 frags/lane in registers from coalesced WT2 layout.
// sAgg/sH: 16B-unit XOR-swizzled (unit ^ row&7) -> conflict-free ds_read_b128.
__global__ __launch_bounds__(512, 2) void layer_k(
    const unsigned short* __restrict__ hb,
    const int* __restrict__ rowptr, const int* __restrict__ eidx,
    const unsigned short* __restrict__ WT2, const float* __restrict__ bl,
    unsigned short* __restrict__ hout, float* __restrict__ hgmax) {
  __shared__ unsigned short sAgg[64 * 128];   // 16 KB (reused as sOut)
  __shared__ unsigned short sH[64 * 128];     // 16 KB
  __shared__ float sred[8][64];
  __shared__ float sinv[64];
  int tid = threadIdx.x;
  int r0 = blockIdx.x * 64;
  int lane = tid & 63, w = tid >> 6;
  int l16 = lane & 15, hi = lane >> 4;

  // ---- weights & bias (issue first; independent of gather) ----
  s16x8 wf[8];                                // f = m*4+kk
  #pragma unroll
  for (int f = 0; f < 8; ++f)
    wf[f] = *(const s16x8*)&WT2[w * 4096 + f * 512 + lane * 8];
  float bb = bl[w * 16 + l16];

  // ---- gather phase: 32 groups of 16 lanes, 2 nodes each ----
  {
    int gid = tid >> 4, gl = tid & 15;
    #pragma unroll
    for (int s = 0; s < 2; ++s) {
      int rl = gid * 2 + s;                   // local row 0..63
      int node = r0 + rl; if (node > NN - 1) node = NN - 1;
      int st = rowptr[node], en = rowptr[node + 1];
      u16x8 own = *(const u16x8*)&hb[node * 128 + gl * 8];
      *(u16x8*)&sH[rl * 128 + ((gl ^ (rl & 7)) * 8)] = own;
      float acc[8] = {0.f, 0.f, 0.f, 0.f, 0.f, 0.f, 0.f, 0.f};
      for (int e = st; e < en; e += 4) {
        int e1 = e + 1 < en ? e + 1 : en - 1;
        int e2 = e + 2 < en ? e + 2 : en - 1;
        int e3 = e + 3 < en ? e + 3 : en - 1;
        int s0 = eidx[e], s1 = eidx[e1], s2 = eidx[e2], s3 = eidx[e3];
        u16x8 v0 = *(const u16x8*)&hb[s0 * 128 + gl * 8];
        u16x8 v1 = *(const u16x8*)&hb[s1 * 128 + gl * 8];
        u16x8 v2 = *(const u16x8*)&hb[s2 * 128 + gl * 8];
        u16x8 v3 = *(const u16x8*)&hb[s3 * 128 + gl * 8];
        float m1 = (e + 1 < en) ? 1.f : 0.f;
        float m2 = (e + 2 < en) ? 1.f : 0.f;
        float m3 = (e + 3 < en) ? 1.f : 0.f;
        #pragma unroll
        for (int j = 0; j < 8; ++j) {
          acc[j] += b2f(v0[j]);
          acc[j] += m1 * b2f(v1[j]);
          acc[j] += m2 * b2f(v2[j]);
          acc[j] += m3 * b2f(v3[j]);
        }
      }
      int cnt = en - st;
      float inv = 1.f / (float)(cnt > 0 ? cnt : 1);
      u16x8 o;
      #pragma unroll
      for (int j = 0; j < 8; ++j) o[j] = f2b(acc[j] * inv);
      *(u16x8*)&sAgg[rl * 128 + ((gl ^ (rl & 7)) * 8)] = o;
    }
  }
  __syncthreads();

  // ---- MFMA: 4 row-tiles x this wave's col-tile ----
  f32x4 acc[4];
  #pragma unroll
  for (int rt = 0; rt < 4; ++rt) acc[rt] = (f32x4){0.f, 0.f, 0.f, 0.f};
  #pragma unroll
  for (int kk = 0; kk < 4; ++kk) {
    int au = ((kk * 4 + hi) ^ (l16 & 7)) * 8;
    #pragma unroll
    for (int rt = 0; rt < 4; ++rt) {
      s16x8 a = *(const s16x8*)&sAgg[(rt * 16 + l16) * 128 + au];
      s16x8 h = *(const s16x8*)&sH[(rt * 16 + l16) * 128 + au];
      acc[rt] = __builtin_amdgcn_mfma_f32_16x16x32_bf16(a, wf[kk], acc[rt], 0, 0, 0);
      acc[rt] = __builtin_amdgcn_mfma_f32_16x16x32_bf16(h, wf[4 + kk], acc[rt], 0, 0, 0);
    }
  }

  // ---- bias + partial row-norm (this wave's 16 cols) ----
  float v[4][4];
  #pragma unroll
  for (int rt = 0; rt < 4; ++rt) {
    float ss[4];
    #pragma unroll
    for (int i = 0; i < 4; ++i) {
      float t = acc[rt][i] + bb;
      v[rt][i] = t;
      ss[i] = t * t;
    }
    #pragma unroll
    for (int m = 1; m < 16; m <<= 1) {
      #pragma unroll
      for (int i = 0; i < 4; ++i) ss[i] += __shfl_xor(ss[i], m);
    }
    if (l16 == 0) {
      #pragma unroll
      for (int i = 0; i < 4; ++i) sred[w][rt * 16 + hi * 4 + i] = ss[i];
    }
  }
  __syncthreads();
  if (tid < 64) {
    float s = 0.f;
    #pragma unroll
    for (int ww = 0; ww < 8; ++ww) s += sred[ww][tid];
    sinv[tid] = 1.f / fmaxf(sqrtf(s), 1e-12f);
  }
  __syncthreads();

  // ---- relu + store to sOut (swizzled 32B chunks) + fused pool (layer 3) ----
  #pragma unroll
  for (int rt = 0; rt < 4; ++rt) {
    float vm = 0.f;
    #pragma unroll
    for (int i = 0; i < 4; ++i) {
      int row = rt * 16 + hi * 4 + i;
      float r = fmaxf(v[rt][i] * sinv[row], 0.f);
      v[rt][i] = r;
      vm = fmaxf(vm, r);
      sAgg[row * 128 + ((w ^ (row & 7)) * 16) + l16] = f2b(r);
    }
    if (hgmax) {
      int rsb = r0 + rt * 16 + hi * 4;        // 4-row strips never cross graphs
      if (rsb < NN)
        atomicMax((int*)&hgmax[(rsb / 200) * 128 + w * 16 + l16], __float_as_int(vm));
    }
  }
  __syncthreads();

  // ---- coalesced read-back & store: 2KB contiguous per instruction ----
  {
    int rr = tid >> 3, q = tid & 7;
    int row = r0 + rr;
    if (row < NN) {
      int sb = rr * 128 + ((q ^ (rr & 7)) * 16);
      u16x8 p0 = *(const u16x8*)&sAgg[sb];
      u16x8 p1 = *(const u16x8*)&sAgg[sb + 8];
      *(u16x8*)&hout[row * 128 + q * 16] = p0;
      *(u16x8*)&hout[row * 128 + q * 16 + 8] = p1;
    }
  }
}

// ---------- final: news + lin2 + lin3 + sigmoid ----------
__global__ __launch_bounds__(128) void final_k(
    const float* __restrict__ hg, const int* __restrict__ root,
    const float* __restrict__ x,
    const float* __restrict__ Wn, const float* __restrict__ bn,
    const float* __restrict__ W2, const float* __restrict__ b2,
    const float* __restrict__ W3, const float* __restrict__ b3,
    float* __restrict__ out) {
  __shared__ float hgr[128];
  __shared__ float xr[128];
  __shared__ float red[2];
  int g = blockIdx.x, j = threadIdx.x;
  int rt = root[g];
  hgr[j] = hg[g * HH + j];
  xr[j] = x[rt * HH + j];
  __syncthreads();
  float acc2 = b2[j];
  float accn = bn[j];
  for (int k = 0; k < 128; ++k) {
    acc2 += hgr[k] * W2[k * HH + j];
    accn += xr[k] * Wn[k * HH + j];
  }
  float c = fmaxf(acc2, 0.f) * W3[j] + fmaxf(accn, 0.f) * W3[HH + j];
  #pragma unroll
  for (int d = 1; d < 64; d <<= 1) c += __shfl_xor(c, d);
  if ((j & 63) == 0) red[j >> 6] = c;
  __syncthreads();
  if (j == 0) out[g] = 1.f / (1.f + expf(-(red[0] + red[1] + b3[0])));
}

extern "C" void kernel_launch(void* const* d_in, const int* in_sizes, int n_in,
                              void* d_out, int out_size, void* d_ws, size_t ws_size,
                              hipStream_t stream) {
  const float* x     = (const float*)d_in[0];
  const int*   adj   = (const int*)d_in[1];
  const int*   batch = (const int*)d_in[2];
  const float *W1l = (const float*)d_in[3],  *b1l = (const float*)d_in[4],  *W1r = (const float*)d_in[5];
  const float *W2l = (const float*)d_in[6],  *b2l = (const float*)d_in[7],  *W2r = (const float*)d_in[8];
  const float *W3l = (const float*)d_in[9],  *b3l = (const float*)d_in[10], *W3r = (const float*)d_in[11];
  const float *Wnews = (const float*)d_in[12], *bnews = (const float*)d_in[13];
  const float *Wlin2 = (const float*)d_in[14], *blin2 = (const float*)d_in[15];
  const float *Wlin3 = (const float*)d_in[16], *blin3 = (const float*)d_in[17];
  float* out = (float*)d_out;

  const int* srcp = adj;
  const int* dstp = adj + EE;

  char* ws = (char*)d_ws;
  size_t off = 0;
  auto alloc = [&](size_t bytes) -> void* {
    void* p = ws + off;
    off = (off + bytes + 255) & ~(size_t)255;
    return p;
  };
  int*   deg    = (int*)alloc(sizeof(int) * NN);
  int*   excl   = (int*)alloc(sizeof(int) * NN);
  int*   bsum   = (int*)alloc(sizeof(int) * 64);
  int*   rowptr = (int*)alloc(sizeof(int) * (NN + 1));
  int*   wp     = (int*)alloc(sizeof(int) * NN);
  int*   root   = (int*)alloc(sizeof(int) * GG);
  int*   eidx   = (int*)alloc(sizeof(int) * EE);
  unsigned short* WT = (unsigned short*)alloc(sizeof(short) * 6 * 128 * 128);
  unsigned short* xb = (unsigned short*)alloc(sizeof(short) * NN * HH);
  unsigned short* h1 = (unsigned short*)alloc(sizeof(short) * NN * HH);
  unsigned short* h2 = (unsigned short*)alloc(sizeof(short) * NN * HH);
  float* hg = (float*)alloc(sizeof(float) * GG * HH);
  (void)ws_size; (void)n_in; (void)in_sizes; (void)out_size;

  prep_k<<<B_CVT + B_W + B_ROOT + B_ZD + B_ZH, 256, 0, stream>>>(
      x, xb, W1l, W1r, W2l, W2r, W3l, W3r, WT, deg, batch, root, hg);
  hist_k<<<(EE + 255) / 256, 256, 0, stream>>>(dstp, deg);
  scan1_k<<<(NN + 1023) / 1024, 1024, 0, stream>>>(deg, excl, bsum);
  scanB_k<<<(NN + 255) / 256, 256, 0, stream>>>(excl, bsum, rowptr, wp);
  scatter_k<<<(EE + 255) / 256, 256, 0, stream>>>(srcp, dstp, wp, eidx);

  const int LGRID = (NN + 63) / 64;          // 782

  layer_k<<<LGRID, 512, 0, stream>>>(xb, rowptr, eidx, WT + 0 * 32768, b1l, h1, nullptr);
  layer_k<<<LGRID, 512, 0, stream>>>(h1, rowptr, eidx, WT + 1 * 32768, b2l, h2, nullptr);
  layer_k<<<LGRID, 512, 0, stream>>>(h2, rowptr, eidx, WT + 2 * 32768, b3l, h1, hg);

  final_k<<<GG, 128, 0, stream>>>(hg, root, x, Wnews, bnews,
                                  Wlin2, blin2, Wlin3, blin3, out);
}